// Round 20
// baseline (128.028 us; speedup 1.0000x reference)
//
#include <hip/hip_runtime.h>
#include <hip/hip_bf16.h>
#include <math.h>

typedef __hip_bfloat16 bf16;
typedef __attribute__((ext_vector_type(4))) float f32x4;
typedef __attribute__((ext_vector_type(8))) short short8;
typedef __attribute__((ext_vector_type(4))) unsigned short u16x4;

#define HIDN 768
#define NTOK 2048   // B*S
#define NH 12
#define HD 64
#define ISZ 3072
#define SEQ 512

__device__ __forceinline__ bf16 f2bf(float x){ return __float2bfloat16(x); }
__device__ __forceinline__ float bf2f(unsigned short u){ return __uint_as_float(((unsigned)u)<<16); }
// Polynomial gelu (r15-proven): Phi ~= med3(0.5 + x*(a1+a3x^2+a5x^4), 0, 1).
__device__ __forceinline__ float gelu_fast(float x){
    float u = x*x;
    float g = fmaf(u, fmaf(u, 0.00340656f, -0.0530184f), 0.393242f);
    float phi = __builtin_amdgcn_fmed3f(fmaf(x, g, 0.5f), 0.f, 1.f);
    return x * phi;
}

// async global->LDS, 16B per lane (LDS dest = wave base + lane*16)
__device__ __forceinline__ void gload16(const bf16* g, bf16* l){
    __builtin_amdgcn_global_load_lds(
        (const __attribute__((address_space(1))) unsigned int*)g,
        (__attribute__((address_space(3))) unsigned int*)l,
        16, 0, 0);
}

#define FENCE asm volatile("" ::: "memory")

// ---------------------------------------------------------------------------
// Pipelined GEMM core (K=768, 512 thr = 8 waves 4Mx2N, tile 128x64, BK=64,
// 2 LDS buffers, counted vmcnt(3), XOR-swizzled LDS, setprio). r10-proven.
// gemm_pipe<EPI=1>: FFN2 split-K partials -> bf16 store (z-batched).
// ---------------------------------------------------------------------------
template<int EPI>
__global__ __launch_bounds__(512)
void gemm_pipe(const bf16* __restrict__ A, const bf16* __restrict__ B,
               void* __restrict__ Cbase, const float* __restrict__ bias,
               int lda, int ldb, int ldc,
               long sAz, long sBz, long sCz)
{
    __shared__ __align__(16) char hlds[2*24576];
    int z = blockIdx.z;
    A += (long)z*sAz; B += (long)z*sBz;

    int nwg  = gridDim.x * gridDim.y;
    int orig = blockIdx.y * gridDim.x + blockIdx.x;
    int q8 = nwg >> 3, r8 = nwg & 7;
    int xcd = orig & 7, idx = orig >> 3;
    int wg = (xcd < r8 ? xcd*(q8+1) : r8*(q8+1) + (xcd-r8)*q8) + idx;
    int bn = wg % gridDim.x, bm = wg / gridDim.x;

    int t = threadIdx.x;
    int wave = t >> 6, lane = t & 63;
    int wm = (wave >> 1) << 5;
    int wn = (wave & 1) << 5;
    int lr = lane & 15, lg = lane >> 4;
    int x7 = lr & 7;
    int gb0 = ((lg    ) ^ x7) << 4;
    int gb1 = ((4 | lg) ^ x7) << 4;

    int srow = t >> 3;
    int glog = (t & 7) ^ (srow & 7);
    const bf16* Ag0 = A + (long)(bm*128 + srow)*lda + glog*8;
    const bf16* Ag1 = Ag0 + (long)64*lda;
    const bf16* Bg0 = B + (long)(bn*64 + srow)*ldb + glog*8;

#define PSTAGE(buf,kt) { \
    gload16(Ag0 + (kt)*64, (bf16*)(hlds + (buf)*24576 + t*16)); \
    gload16(Ag1 + (kt)*64, (bf16*)(hlds + (buf)*24576 + 8192 + t*16)); \
    gload16(Bg0 + (kt)*64, (bf16*)(hlds + (buf)*24576 + 16384 + t*16)); }

    PSTAGE(0, 0);

    f32x4 acc[2][2] = {};

    #pragma unroll
    for (int kt = 0; kt < 12; ++kt){
        if (kt < 11) PSTAGE((kt+1)&1, kt+1);
        if (kt < 11) asm volatile("s_waitcnt vmcnt(3)" ::: "memory");
        else         asm volatile("s_waitcnt vmcnt(0)" ::: "memory");
        FENCE; __builtin_amdgcn_s_barrier(); FENCE;

        const char* Lb = hlds + (kt&1)*24576;
        short8 af[2][2], bfr[2][2];
        #pragma unroll
        for (int m=0;m<2;m++){
            const char* pr = Lb + (wm + m*16 + lr)*128;
            af[m][0] = *(const short8*)(pr + gb0);
            af[m][1] = *(const short8*)(pr + gb1);
        }
        #pragma unroll
        for (int n=0;n<2;n++){
            const char* pr = Lb + 16384 + (wn + n*16 + lr)*128;
            bfr[n][0] = *(const short8*)(pr + gb0);
            bfr[n][1] = *(const short8*)(pr + gb1);
        }
        __builtin_amdgcn_s_setprio(1);
        #pragma unroll
        for (int m=0;m<2;m++)
            #pragma unroll
            for (int n=0;n<2;n++)
                #pragma unroll
                for (int kk=0;kk<2;kk++)
                    acc[m][n] = __builtin_amdgcn_mfma_f32_16x16x32_bf16(af[m][kk], bfr[n][kk], acc[m][n], 0,0,0);
        __builtin_amdgcn_s_setprio(0);
        FENCE; __builtin_amdgcn_s_barrier(); FENCE;
    }
#undef PSTAGE

    #pragma unroll
    for (int m=0;m<2;m++){
        #pragma unroll
        for (int n=0;n<2;n++){
            int col = bn*64 + wn + n*16 + lr;
            #pragma unroll
            for (int i=0;i<4;i++){
                long row = (long)bm*128 + wm + m*16 + lg*4 + i;
                ((bf16*)Cbase + (long)z*sCz)[row*ldc+col] = f2bf(acc[m][n][i]);
            }
        }
    }
}

// ---------------------------------------------------------------------------
// Fused pre-GEMM: one launch, three segments (all K=768, same pipeline).
//   [0,48):    bhc  = bo_pad[128,768] @ WiT^T   -> f32 [12][3072], row<12
//   [48,336):  WcT  = WiT[3072,768] @ Wobf^T    -> bf16, * w_kp[col>>6]
//   [336,912): qkv  = hbf[2048,768] @ WqkvT^T   -> bf16, + bqkv[col]
// ---------------------------------------------------------------------------
__global__ __launch_bounds__(512)
void gemm_pre(const bf16* __restrict__ WiT, const bf16* __restrict__ Wobf,
              const bf16* __restrict__ bo_pad, const bf16* __restrict__ hbf,
              const bf16* __restrict__ WqkvT,
              bf16* __restrict__ WcT, float* __restrict__ bhc,
              bf16* __restrict__ qkv,
              const float* __restrict__ w_kp, const float* __restrict__ bi,
              const float* __restrict__ bqkv)
{
    __shared__ __align__(16) char hlds[2*24576];
    int bid = blockIdx.x;
    int mode, local, gx, nwg, ldc;
    const bf16 *A, *B;
    if (bid < 48){        mode=0; local=bid;     gx=48; nwg=48;  A=bo_pad; B=WiT;   ldc=ISZ; }
    else if (bid < 336){  mode=1; local=bid-48;  gx=12; nwg=288; A=WiT;    B=Wobf;  ldc=HIDN; }
    else {                mode=2; local=bid-336; gx=36; nwg=576; A=hbf;    B=WqkvT; ldc=3*HIDN; }

    int cpx = nwg >> 3;
    int wg = (local & 7)*cpx + (local >> 3);   // nwg%8==0 for all segments
    int bn = wg % gx, bm = wg / gx;

    int t = threadIdx.x;
    int wave = t >> 6, lane = t & 63;
    int wm = (wave >> 1) << 5;
    int wn = (wave & 1) << 5;
    int lr = lane & 15, lg = lane >> 4;
    int x7 = lr & 7;
    int gb0 = ((lg    ) ^ x7) << 4;
    int gb1 = ((4 | lg) ^ x7) << 4;

    int srow = t >> 3;
    int glog = (t & 7) ^ (srow & 7);
    const bf16* Ag0 = A + (long)(bm*128 + srow)*HIDN + glog*8;
    const bf16* Ag1 = Ag0 + (long)64*HIDN;
    const bf16* Bg0 = B + (long)(bn*64 + srow)*HIDN + glog*8;

#define PSTAGE(buf,kt) { \
    gload16(Ag0 + (kt)*64, (bf16*)(hlds + (buf)*24576 + t*16)); \
    gload16(Ag1 + (kt)*64, (bf16*)(hlds + (buf)*24576 + 8192 + t*16)); \
    gload16(Bg0 + (kt)*64, (bf16*)(hlds + (buf)*24576 + 16384 + t*16)); }

    PSTAGE(0, 0);

    f32x4 acc[2][2] = {};

    #pragma unroll
    for (int kt = 0; kt < 12; ++kt){
        if (kt < 11) PSTAGE((kt+1)&1, kt+1);
        if (kt < 11) asm volatile("s_waitcnt vmcnt(3)" ::: "memory");
        else         asm volatile("s_waitcnt vmcnt(0)" ::: "memory");
        FENCE; __builtin_amdgcn_s_barrier(); FENCE;

        const char* Lb = hlds + (kt&1)*24576;
        short8 af[2][2], bfr[2][2];
        #pragma unroll
        for (int m=0;m<2;m++){
            const char* pr = Lb + (wm + m*16 + lr)*128;
            af[m][0] = *(const short8*)(pr + gb0);
            af[m][1] = *(const short8*)(pr + gb1);
        }
        #pragma unroll
        for (int n=0;n<2;n++){
            const char* pr = Lb + 16384 + (wn + n*16 + lr)*128;
            bfr[n][0] = *(const short8*)(pr + gb0);
            bfr[n][1] = *(const short8*)(pr + gb1);
        }
        __builtin_amdgcn_s_setprio(1);
        #pragma unroll
        for (int m=0;m<2;m++)
            #pragma unroll
            for (int n=0;n<2;n++)
                #pragma unroll
                for (int kk=0;kk<2;kk++)
                    acc[m][n] = __builtin_amdgcn_mfma_f32_16x16x32_bf16(af[m][kk], bfr[n][kk], acc[m][n], 0,0,0);
        __builtin_amdgcn_s_setprio(0);
        FENCE; __builtin_amdgcn_s_barrier(); FENCE;
    }
#undef PSTAGE

    #pragma unroll
    for (int m=0;m<2;m++){
        #pragma unroll
        for (int n=0;n<2;n++){
            int col = bn*64 + wn + n*16 + lr;
            #pragma unroll
            for (int i=0;i<4;i++){
                long row = (long)bm*128 + wm + m*16 + lg*4 + i;
                float v = acc[m][n][i];
                if (mode == 0){
                    if (row < NH) bhc[row*ISZ+col] = fmaf(w_kp[row], v, bi[col]);
                } else if (mode == 1){
                    WcT[row*HIDN+col] = f2bf(v * w_kp[col>>6]);
                } else {
                    qkv[row*(3*HIDN)+col] = f2bf(v + bqkv[col]);
                }
            }
        }
    }
}

// ---------------------------------------------------------------------------
// Fused flash attention v2 (max-free single pass + kt-split across 2 waves).
// ---------------------------------------------------------------------------
__global__ __launch_bounds__(256)
void flash_attn(const bf16* __restrict__ qkv, const bf16* __restrict__ Vt,
                const float* __restrict__ mask, bf16* __restrict__ ctx2)
{
    __shared__ __align__(16) char p_lds[4*2048];    // per-wave P scratch
    __shared__ float mrg[2][64][21];                // kh=1 partials
    int z = blockIdx.y;
    int b = z / NH, h = z - b*NH;
    int t = threadIdx.x;
    int wave = t >> 6, lane = t & 63;
    int qg = wave >> 1, kh = wave & 1;
    int q0 = blockIdx.x*32 + qg*16;
    int lr = lane & 15, lg = lane >> 4;
    int x7 = lr & 7;
    int gb0 = ((lg    ) ^ x7) << 4;
    int gb1 = ((4 | lg) ^ x7) << 4;

    const bf16* Qp = qkv + (long)(b*SEQ + q0 + lr)*(3*HIDN) + h*HD + lg*8;
    short8 aq0 = *(const short8*)(Qp);
    short8 aq1 = *(const short8*)(Qp + 32);

    const bf16* Kb = qkv + (long)b*SEQ*(3*HIDN) + HIDN + h*HD + lg*8;
    const bf16* Vb = Vt + (long)z*HD*SEQ;
    const float* mb = mask + b*SEQ;
    char* pw = p_lds + wave*2048;

    f32x4 o[4] = {};
    float lsum[4] = {0.f,0.f,0.f,0.f};

    for (int kt = kh*4; kt < kh*4 + 4; ++kt){
        int kbase = kt*64;
        short8 bk0[4], bk1[4];
        #pragma unroll
        for (int nf=0;nf<4;nf++){
            const bf16* kp = Kb + (long)(kbase + nf*16 + lr)*(3*HIDN);
            bk0[nf] = *(const short8*)(kp);
            bk1[nf] = *(const short8*)(kp + 32);
        }
        f32x4 s[4] = {};
        #pragma unroll
        for (int nf=0;nf<4;nf++){
            s[nf] = __builtin_amdgcn_mfma_f32_16x16x32_bf16(aq0, bk0[nf], s[nf], 0,0,0);
            s[nf] = __builtin_amdgcn_mfma_f32_16x16x32_bf16(aq1, bk1[nf], s[nf], 0,0,0);
        }
        short8 bv0[4], bv1[4];
        #pragma unroll
        for (int nf=0;nf<4;nf++){
            const bf16* vp = Vb + (long)(nf*16 + lr)*SEQ + kbase + lg*8;
            bv0[nf] = *(const short8*)(vp);
            bv1[nf] = *(const short8*)(vp + 32);
        }
        #pragma unroll
        for (int nf=0;nf<4;nf++){
            float mk = mb[kbase + nf*16 + lr];
            int gk = nf*2 + (lr>>3);
            #pragma unroll
            for (int i=0;i<4;i++){
                int q = lg*4 + i;
                float e = __expf(fmaf(s[nf][i], 0.125f, mk));
                lsum[i] += e;
                *(bf16*)(pw + q*128 + ((gk ^ (q&7))<<4) + (lr&7)*2) = f2bf(e);
            }
        }
        short8 ap0 = *(const short8*)(pw + lr*128 + gb0);
        short8 ap1 = *(const short8*)(pw + lr*128 + gb1);
        #pragma unroll
        for (int nf=0;nf<4;nf++){
            o[nf] = __builtin_amdgcn_mfma_f32_16x16x32_bf16(ap0, bv0[nf], o[nf], 0,0,0);
            o[nf] = __builtin_amdgcn_mfma_f32_16x16x32_bf16(ap1, bv1[nf], o[nf], 0,0,0);
        }
    }

    if (kh == 1){
        float* m = &mrg[qg][lane][0];
        #pragma unroll
        for (int nf=0;nf<4;nf++)
            #pragma unroll
            for (int i=0;i<4;i++) m[nf*4+i] = o[nf][i];
        #pragma unroll
        for (int i=0;i<4;i++) m[16+i] = lsum[i];
    }
    __syncthreads();
    if (kh == 1) return;

    {
        const float* m = &mrg[qg][lane][0];
        #pragma unroll
        for (int nf=0;nf<4;nf++)
            #pragma unroll
            for (int i=0;i<4;i++) o[nf][i] += m[nf*4+i];
        #pragma unroll
        for (int i=0;i<4;i++) lsum[i] += m[16+i];
    }

    #pragma unroll
    for (int i=0;i<4;i++){
        float v = lsum[i];
        v += __shfl_xor(v, 1, 64);
        v += __shfl_xor(v, 2, 64);
        v += __shfl_xor(v, 4, 64);
        v += __shfl_xor(v, 8, 64);
        lsum[i] = __builtin_amdgcn_rcpf(v);
    }
    bf16* Cp = ctx2 + (long)(b*SEQ + q0)*HIDN + h*HD;
    #pragma unroll
    for (int nf=0;nf<4;nf++)
        #pragma unroll
        for (int i=0;i<4;i++)
            Cp[(long)(lg*4+i)*HIDN + nf*16 + lr] = f2bf(o[nf][i] * lsum[i]);
}

// ---------------------------------------------------------------------------
// Fused per-head FFN1 + head reduction — v6: tile 128x96, grid 512 = exactly
// 2 blocks/CU single round. NO occupancy bound (r18's spill cause removed);
// register economy: no wav[] preload (w_a read per-merge, wave-uniform).
// Correctness of this tiling/staging validated in r18 (absmax 0.0156).
// S[t][i] = sum_h w_a[h]*gelu( (ctx2[t]@WcT'[i])_h + bhc[h][i] )
// ---------------------------------------------------------------------------
__global__ __launch_bounds__(512)
void gemm_heads(const bf16* __restrict__ A, const bf16* __restrict__ B,
                bf16* __restrict__ S, const float* __restrict__ bhc,
                const float* __restrict__ w_a)
{
    __shared__ __align__(16) char hlds[2*28672 + 4608];   // 2x(A16K+B12K) + bhc
    char* bhcl = hlds + 57344;

    int nwg  = gridDim.x * gridDim.y;             // 512
    int orig = blockIdx.y * gridDim.x + blockIdx.x;
    int cpx = nwg >> 3;
    int wg = (orig & 7)*cpx + (orig >> 3);
    int bn = wg % gridDim.x, bm = wg / gridDim.x; // bn in [0,32), bm in [0,16)

    int t = threadIdx.x;
    int wave = t >> 6, lane = t & 63;
    int wm = (wave >> 1) << 5;    // 0,32,64,96
    int wn = (wave & 1) * 48;     // 0,48
    int lr = lane & 15, lg = lane >> 4;
    int x7 = lr & 7;
    int gb0 = ((lg    ) ^ x7) << 4;
    int gb1 = ((4 | lg) ^ x7) << 4;

    int srow = t >> 3;
    int glog = (t & 7) ^ (srow & 7);
    const bf16* Ag0 = A + (long)(bm*128 + srow)*HIDN + glog*8;
    const bf16* Ag1 = Ag0 + (long)64*HIDN;
    const bf16* Bg0 = B + (long)(bn*96 + srow)*HIDN + glog*8;   // rows 0-47 (waves 0-5)
    const bf16* Bg1 = Bg0 + (long)48*HIDN;                      // rows 48-95

    // stage this block's bhc tile [12][96] f32 (288 float4) into LDS
    if (t < 288){
        int hh = t / 24, cc = (t % 24) * 4;
        float4 v = *(const float4*)&bhc[hh*ISZ + bn*96 + cc];
        *(float4*)(bhcl + t*16) = v;
    }
    asm volatile("s_waitcnt vmcnt(0)" ::: "memory");   // drain bhc loads before counting

#define HSTAGE(buf,h) { \
    gload16(Ag0 + (h)*64, (bf16*)(hlds + (buf)*28672 + t*16)); \
    gload16(Ag1 + (h)*64, (bf16*)(hlds + (buf)*28672 + 8192 + t*16)); \
    if (wave < 6){ \
        gload16(Bg0 + (h)*64, (bf16*)(hlds + (buf)*28672 + 16384 + t*16)); \
        gload16(Bg1 + (h)*64, (bf16*)(hlds + (buf)*28672 + 22528 + t*16)); \
    } }

    HSTAGE(0, 0);

    f32x4 acc[2][3] = {};
    f32x4 sacc[2][3] = {};

    #pragma unroll
    for (int h = 0; h < NH; ++h){
        if (h < NH-1) HSTAGE((h+1)&1, h+1);
        if (h > 0){
            float wa = w_a[h-1];
            float bh[3];
            #pragma unroll
            for (int n=0;n<3;n++)
                bh[n] = *(const float*)(bhcl + (h-1)*384 + (wn + n*16 + lr)*4);
            #pragma unroll
            for (int m=0;m<2;m++)
                #pragma unroll
                for (int n=0;n<3;n++)
                    #pragma unroll
                    for (int i=0;i<4;i++){
                        float v = acc[m][n][i] + bh[n];
                        sacc[m][n][i] = fmaf(wa, gelu_fast(v), sacc[m][n][i]);
                        acc[m][n][i] = 0.f;
                    }
        }
        if (h < NH-1){
            if (wave < 6) asm volatile("s_waitcnt vmcnt(4)" ::: "memory");
            else          asm volatile("s_waitcnt vmcnt(2)" ::: "memory");
        } else {
            asm volatile("s_waitcnt vmcnt(0)" ::: "memory");
        }
        FENCE; __builtin_amdgcn_s_barrier(); FENCE;

        const char* Lb = hlds + (h&1)*28672;
        short8 af[2][2], bfr[3][2];
        #pragma unroll
        for (int m=0;m<2;m++){
            const char* pr = Lb + (wm + m*16 + lr)*128;
            af[m][0] = *(const short8*)(pr + gb0);
            af[m][1] = *(const short8*)(pr + gb1);
        }
        #pragma unroll
        for (int n=0;n<3;n++){
            const char* pr = Lb + 16384 + (wn + n*16 + lr)*128;
            bfr[n][0] = *(const short8*)(pr + gb0);
            bfr[n][1] = *(const short8*)(pr + gb1);
        }
        __builtin_amdgcn_s_setprio(1);
        #pragma unroll
        for (int m=0;m<2;m++)
            #pragma unroll
            for (int n=0;n<3;n++)
                #pragma unroll
                for (int kk=0;kk<2;kk++)
                    acc[m][n] = __builtin_amdgcn_mfma_f32_16x16x32_bf16(af[m][kk], bfr[n][kk], acc[m][n], 0,0,0);
        __builtin_amdgcn_s_setprio(0);
        FENCE; __builtin_amdgcn_s_barrier(); FENCE;
    }
#undef HSTAGE

    {   // final head merge
        float wa = w_a[NH-1];
        float bh[3];
        #pragma unroll
        for (int n=0;n<3;n++)
            bh[n] = *(const float*)(bhcl + (NH-1)*384 + (wn + n*16 + lr)*4);
        #pragma unroll
        for (int m=0;m<2;m++)
            #pragma unroll
            for (int n=0;n<3;n++)
                #pragma unroll
                for (int i=0;i<4;i++){
                    float v = acc[m][n][i] + bh[n];
                    sacc[m][n][i] = fmaf(wa, gelu_fast(v), sacc[m][n][i]);
                }
    }

    #pragma unroll
    for (int m=0;m<2;m++)
        #pragma unroll
        for (int n=0;n<3;n++)
            #pragma unroll
            for (int i=0;i<4;i++){
                long row = (long)bm*128 + wm + m*16 + lg*4 + i;
                S[row*ISZ + bn*96 + wn + n*16 + lr] = f2bf(sacc[m][n][i]);
            }
}

// ---------------------------------------------------------------------------
// One launch: weight transposes (blocks < 6336) + elementwise prep (rest).
// ---------------------------------------------------------------------------
#define NPREP (NTOK*HIDN + HIDN*HIDN + 128*HIDN + 3*HIDN)
__global__ __launch_bounds__(256)
void prep_all(const float* __restrict__ Wq, const float* __restrict__ Wk,
              const float* __restrict__ Wv, const float* __restrict__ Wi,
              const float* __restrict__ Wout,
              bf16* __restrict__ WqkvT, bf16* __restrict__ WiT,
              bf16* __restrict__ WoutT,
              const float* __restrict__ hidden, const float* __restrict__ Wo,
              const float* __restrict__ bq, const float* __restrict__ bk,
              const float* __restrict__ bv, const float* __restrict__ bo,
              bf16* __restrict__ hbf, bf16* __restrict__ Wobf,
              float* __restrict__ bqkv, bf16* __restrict__ bo_pad)
{
    __shared__ float tile[32][33];
    int bid = blockIdx.x;
    if (bid >= 6336){
        int i = (bid-6336)*256 + threadIdx.x;
        const int n1 = NTOK*HIDN, n2 = HIDN*HIDN, n3 = 128*HIDN;
        if (i < n1) hbf[i] = f2bf(hidden[i]);
        int j = i - n1;
        if (j >= 0 && j < n2) Wobf[j] = f2bf(Wo[j]);
        int k = i - n1 - n2;
        if (k >= 0 && k < n3) bo_pad[k] = (k < NH*HIDN) ? f2bf(bo[k]) : f2bf(0.f);
        int l = i - n1 - n2 - n3;
        if (l >= 0 && l < 3*HIDN)
            bqkv[l] = (l < HIDN) ? bq[l] : (l < 2*HIDN ? bk[l-HIDN] : bv[l-2*HIDN]);
        return;
    }
    const float* src; bf16* dst; int R, C, ct, rem;
    if (bid < 1728){
        int z = bid / 576; rem = bid - z*576;
        src = (z==0) ? Wq : ((z==1) ? Wk : Wv);
        dst = WqkvT + (long)z*HIDN*HIDN;
        R = HIDN; C = HIDN; ct = 24;
    } else if (bid < 4032){
        rem = bid - 1728; src = Wi; dst = WiT; R = HIDN; C = ISZ; ct = 96;
    } else {
        rem = bid - 4032; src = Wout; dst = WoutT; R = ISZ; C = HIDN; ct = 24;
    }
    int c0 = (rem % ct)*32, r0 = (rem / ct)*32;
    int tx = threadIdx.x & 31, ty = threadIdx.x >> 5;
    #pragma unroll
    for (int i=0;i<32;i+=8) tile[ty+i][tx] = src[(long)(r0+ty+i)*C + c0+tx];
    __syncthreads();
    #pragma unroll
    for (int i=0;i<32;i+=8) dst[(long)(c0+ty+i)*R + r0+tx] = f2bf(tile[tx][ty+i]);
}

// bf16 V transpose: per z=(b,h): qkv V-slice [512 s][64 d] -> Vt[z][64 d][512 s]
__global__ __launch_bounds__(256)
void transpose_v(const bf16* __restrict__ qkv, bf16* __restrict__ Vt)
{
    __shared__ bf16 tile[32][33];
    int za = blockIdx.z; int b = za/NH, h = za - b*NH;
    const bf16* src = qkv + (long)b*SEQ*3*HIDN + 2*HIDN + h*HD;
    bf16* dst = Vt + (long)za*HD*SEQ;
    int d0 = blockIdx.x*32, s0 = blockIdx.y*32;
    int tx = threadIdx.x & 31, ty = threadIdx.x >> 5;
    #pragma unroll
    for (int i=0;i<32;i+=8) tile[ty+i][tx] = src[(long)(s0+ty+i)*(3*HIDN) + d0+tx];
    __syncthreads();
    #pragma unroll
    for (int i=0;i<32;i+=8) dst[(long)(d0+ty+i)*SEQ + s0+tx] = tile[tx][ty+i];
}

// out = LN(hidden + sum_z part_bf16[z] + swa*bout), float4/ushort4 loads.
__global__ __launch_bounds__(192)
void add_ln(const float4* __restrict__ hidden, const u16x4* __restrict__ part,
            const float4* __restrict__ bout, const float* __restrict__ w_a,
            const float4* __restrict__ gamma, const float4* __restrict__ beta,
            float4* __restrict__ out)
{
    __shared__ float red[6];
    int row = blockIdx.x;
    int t = threadIdx.x;          // 0..191
    int wave = t >> 6, lane = t & 63;
    float swa = 0.f;
    #pragma unroll
    for (int h=0;h<NH;h++) swa += w_a[h];

    long idx = (long)row*192 + t;
    float4 x = hidden[idx];
    #pragma unroll
    for (int z=0;z<4;z++){
        u16x4 p = part[(long)z*NTOK*192 + idx];
        x.x += bf2f(p.x); x.y += bf2f(p.y); x.z += bf2f(p.z); x.w += bf2f(p.w);
    }
    float4 bo4 = bout[t];
    x.x += swa*bo4.x; x.y += swa*bo4.y; x.z += swa*bo4.z; x.w += swa*bo4.w;

    float sum = x.x + x.y + x.z + x.w;
    #pragma unroll
    for (int o=32;o>0;o>>=1) sum += __shfl_xor(sum,o,64);
    if (lane==0) red[wave] = sum;
    __syncthreads();
    sum = red[0] + red[1] + red[2];
    float u = sum * (1.0f/768.0f);

    float dx = x.x-u, dy = x.y-u, dz = x.z-u, dw = x.w-u;
    float vs = dx*dx + dy*dy + dz*dz + dw*dw;
    #pragma unroll
    for (int o=32;o>0;o>>=1) vs += __shfl_xor(vs,o,64);
    if (lane==0) red[3+wave] = vs;
    __syncthreads();
    vs = red[3] + red[4] + red[5];
    float rstd = rsqrtf(vs*(1.0f/768.0f) + 1e-12f);

    float4 g = gamma[t], b = beta[t];
    float4 r;
    r.x = g.x*dx*rstd + b.x;
    r.y = g.y*dy*rstd + b.y;
    r.z = g.z*dz*rstd + b.z;
    r.w = g.w*dw*rstd + b.w;
    out[idx] = r;
}

extern "C" void kernel_launch(void* const* d_in, const int* in_sizes, int n_in,
                              void* d_out, int out_size, void* d_ws, size_t ws_size,
                              hipStream_t stream)
{
    const float* hidden = (const float*)d_in[0];
    const float* mask   = (const float*)d_in[1];
    const float* Wq = (const float*)d_in[2];
    const float* bq = (const float*)d_in[3];
    const float* Wk = (const float*)d_in[4];
    const float* bk = (const float*)d_in[5];
    const float* Wv = (const float*)d_in[6];
    const float* bv = (const float*)d_in[7];
    const float* Wo = (const float*)d_in[8];
    const float* bo = (const float*)d_in[9];
    const float* w_kp = (const float*)d_in[10];
    const float* w_a  = (const float*)d_in[11];
    const float* Wi = (const float*)d_in[12];
    const float* bi = (const float*)d_in[13];
    const float* Wout = (const float*)d_in[14];
    const float* boutp = (const float*)d_in[15];
    const float* gamma = (const float*)d_in[16];
    const float* beta  = (const float*)d_in[17];
    float* out = (float*)d_out;

    char* w = (char*)d_ws;
    auto alloc = [&](size_t bytes)->char* {
        char* p = w; w += (bytes + 255) & ~(size_t)255; return p;
    };
    bf16*  hbf    = (bf16*) alloc((size_t)NTOK*HIDN*2);
    bf16*  WqkvT  = (bf16*) alloc((size_t)3*HIDN*HIDN*2);
    float* bqkv   = (float*)alloc((size_t)3*HIDN*4);
    bf16*  WiT    = (bf16*) alloc((size_t)ISZ*HIDN*2);
    bf16*  WoutT  = (bf16*) alloc((size_t)HIDN*ISZ*2);
    bf16*  Wobf   = (bf16*) alloc((size_t)HIDN*HIDN*2);
    bf16*  WcT    = (bf16*) alloc((size_t)ISZ*HIDN*2);
    bf16*  bo_pad = (bf16*) alloc((size_t)128*HIDN*2);
    float* bhc    = (float*)alloc((size_t)NH*ISZ*4);
    bf16*  part   = (bf16*) alloc((size_t)4*NTOK*HIDN*2);   // split-K partials (bf16)
    bf16*  qkv    = (bf16*) alloc((size_t)NTOK*3*HIDN*2);
    bf16*  ctx2   = (bf16*) alloc((size_t)NTOK*HIDN*2);
    bf16*  Sbuf   = (bf16*) alloc((size_t)NTOK*ISZ*2);
    bf16*  Vt     = (bf16*) alloc((size_t)NH*4*HD*SEQ*2);

    // ---- prep (transposes + elementwise, one launch) ----
    prep_all<<<6336 + (NPREP+255)/256, 256, 0, stream>>>(
        Wq, Wk, Wv, Wi, Wout, WqkvT, WiT, WoutT,
        hidden, Wo, bq, bk, bv, bo, hbf, Wobf, bqkv, bo_pad);

    // ---- fused pre-GEMMs: bhc + WcT + QKV in one launch ----
    gemm_pre<<<912, 512, 0, stream>>>(
        WiT, Wobf, bo_pad, hbf, WqkvT,
        WcT, bhc, qkv, w_kp, bi, bqkv);

    // ---- attention ----
    transpose_v<<<dim3(2,16,48), 256, 0, stream>>>(qkv, Vt);
    flash_attn<<<dim3(SEQ/32, 48), 256, 0, stream>>>(qkv, Vt, mask, ctx2);

    // ---- fused per-head FFN1 + head-reduce -> S (128x96 tile, grid 512) ----
    gemm_heads<<<dim3(ISZ/96, NTOK/128), 512, 0, stream>>>(
        ctx2, WcT, Sbuf, bhc, w_a);

    // ---- FFN2': part[z] = S[:, z*768:(z+1)*768] @ WoutT[:, z*768:(z+1)*768]^T (bf16) ----
    gemm_pipe<1><<<dim3(HIDN/64, NTOK/128, 4), 512, 0, stream>>>(
        Sbuf, WoutT, part, nullptr,
        ISZ, ISZ, HIDN,
        768, 768, (long)NTOK*HIDN);

    // ---- residual + partial-sum + swa*bout + LayerNorm ----
    add_ln<<<NTOK, 192, 0, stream>>>(
        (const float4*)hidden, (const u16x4*)part, (const float4*)boutp,
        w_a, (const float4*)gamma, (const float4*)beta, (float4*)out);
}

// Round 21
// 110.487 us; speedup vs baseline: 1.1588x; 1.1588x over previous
//
#include <hip/hip_runtime.h>
#include <hip/hip_bf16.h>
#include <math.h>

typedef __hip_bfloat16 bf16;
typedef __attribute__((ext_vector_type(4))) float f32x4;
typedef __attribute__((ext_vector_type(8))) short short8;
typedef __attribute__((ext_vector_type(4))) unsigned short u16x4;

#define HIDN 768
#define NTOK 2048   // B*S
#define NH 12
#define HD 64
#define ISZ 3072
#define SEQ 512

__device__ __forceinline__ bf16 f2bf(float x){ return __float2bfloat16(x); }
__device__ __forceinline__ float bf2f(unsigned short u){ return __uint_as_float(((unsigned)u)<<16); }
// Polynomial gelu (r15-proven): Phi ~= med3(0.5 + x*(a1+a3x^2+a5x^4), 0, 1).
__device__ __forceinline__ float gelu_fast(float x){
    float u = x*x;
    float g = fmaf(u, fmaf(u, 0.00340656f, -0.0530184f), 0.393242f);
    float phi = __builtin_amdgcn_fmed3f(fmaf(x, g, 0.5f), 0.f, 1.f);
    return x * phi;
}

// async global->LDS, 16B per lane (LDS dest = wave base + lane*16)
__device__ __forceinline__ void gload16(const bf16* g, bf16* l){
    __builtin_amdgcn_global_load_lds(
        (const __attribute__((address_space(1))) unsigned int*)g,
        (__attribute__((address_space(3))) unsigned int*)l,
        16, 0, 0);
}

#define FENCE asm volatile("" ::: "memory")

// ---------------------------------------------------------------------------
// Pipelined GEMM core (K=768, 512 thr = 8 waves 4Mx2N, tile 128x64, BK=64,
// 2 LDS buffers, counted vmcnt(3), XOR-swizzled LDS, setprio). r10-proven.
// gemm_pipe<EPI=1>: FFN2 split-K partials -> bf16 store (z-batched).
// ---------------------------------------------------------------------------
template<int EPI>
__global__ __launch_bounds__(512)
void gemm_pipe(const bf16* __restrict__ A, const bf16* __restrict__ B,
               void* __restrict__ Cbase, const float* __restrict__ bias,
               int lda, int ldb, int ldc,
               long sAz, long sBz, long sCz)
{
    __shared__ __align__(16) char hlds[2*24576];
    int z = blockIdx.z;
    A += (long)z*sAz; B += (long)z*sBz;

    int nwg  = gridDim.x * gridDim.y;
    int orig = blockIdx.y * gridDim.x + blockIdx.x;
    int q8 = nwg >> 3, r8 = nwg & 7;
    int xcd = orig & 7, idx = orig >> 3;
    int wg = (xcd < r8 ? xcd*(q8+1) : r8*(q8+1) + (xcd-r8)*q8) + idx;
    int bn = wg % gridDim.x, bm = wg / gridDim.x;

    int t = threadIdx.x;
    int wave = t >> 6, lane = t & 63;
    int wm = (wave >> 1) << 5;
    int wn = (wave & 1) << 5;
    int lr = lane & 15, lg = lane >> 4;
    int x7 = lr & 7;
    int gb0 = ((lg    ) ^ x7) << 4;
    int gb1 = ((4 | lg) ^ x7) << 4;

    int srow = t >> 3;
    int glog = (t & 7) ^ (srow & 7);
    const bf16* Ag0 = A + (long)(bm*128 + srow)*lda + glog*8;
    const bf16* Ag1 = Ag0 + (long)64*lda;
    const bf16* Bg0 = B + (long)(bn*64 + srow)*ldb + glog*8;

#define PSTAGE(buf,kt) { \
    gload16(Ag0 + (kt)*64, (bf16*)(hlds + (buf)*24576 + t*16)); \
    gload16(Ag1 + (kt)*64, (bf16*)(hlds + (buf)*24576 + 8192 + t*16)); \
    gload16(Bg0 + (kt)*64, (bf16*)(hlds + (buf)*24576 + 16384 + t*16)); }

    PSTAGE(0, 0);

    f32x4 acc[2][2] = {};

    #pragma unroll
    for (int kt = 0; kt < 12; ++kt){
        if (kt < 11) PSTAGE((kt+1)&1, kt+1);
        if (kt < 11) asm volatile("s_waitcnt vmcnt(3)" ::: "memory");
        else         asm volatile("s_waitcnt vmcnt(0)" ::: "memory");
        FENCE; __builtin_amdgcn_s_barrier(); FENCE;

        const char* Lb = hlds + (kt&1)*24576;
        short8 af[2][2], bfr[2][2];
        #pragma unroll
        for (int m=0;m<2;m++){
            const char* pr = Lb + (wm + m*16 + lr)*128;
            af[m][0] = *(const short8*)(pr + gb0);
            af[m][1] = *(const short8*)(pr + gb1);
        }
        #pragma unroll
        for (int n=0;n<2;n++){
            const char* pr = Lb + 16384 + (wn + n*16 + lr)*128;
            bfr[n][0] = *(const short8*)(pr + gb0);
            bfr[n][1] = *(const short8*)(pr + gb1);
        }
        __builtin_amdgcn_s_setprio(1);
        #pragma unroll
        for (int m=0;m<2;m++)
            #pragma unroll
            for (int n=0;n<2;n++)
                #pragma unroll
                for (int kk=0;kk<2;kk++)
                    acc[m][n] = __builtin_amdgcn_mfma_f32_16x16x32_bf16(af[m][kk], bfr[n][kk], acc[m][n], 0,0,0);
        __builtin_amdgcn_s_setprio(0);
        FENCE; __builtin_amdgcn_s_barrier(); FENCE;
    }
#undef PSTAGE

    #pragma unroll
    for (int m=0;m<2;m++){
        #pragma unroll
        for (int n=0;n<2;n++){
            int col = bn*64 + wn + n*16 + lr;
            #pragma unroll
            for (int i=0;i<4;i++){
                long row = (long)bm*128 + wm + m*16 + lg*4 + i;
                ((bf16*)Cbase + (long)z*sCz)[row*ldc+col] = f2bf(acc[m][n][i]);
            }
        }
    }
}

// ---------------------------------------------------------------------------
// Fused pre-GEMM: one launch, three segments (all K=768, same pipeline).
//   [0,48):    bhc  = bo_pad[128,768] @ WiT^T   -> f32 [12][3072], row<12
//   [48,336):  WcT  = WiT[3072,768] @ Wobf^T    -> bf16, * w_kp[col>>6]
//   [336,912): qkv  = hbf[2048,768] @ WqkvT^T   -> bf16, + bqkv[col]
// ---------------------------------------------------------------------------
__global__ __launch_bounds__(512)
void gemm_pre(const bf16* __restrict__ WiT, const bf16* __restrict__ Wobf,
              const bf16* __restrict__ bo_pad, const bf16* __restrict__ hbf,
              const bf16* __restrict__ WqkvT,
              bf16* __restrict__ WcT, float* __restrict__ bhc,
              bf16* __restrict__ qkv,
              const float* __restrict__ w_kp, const float* __restrict__ bi,
              const float* __restrict__ bqkv)
{
    __shared__ __align__(16) char hlds[2*24576];
    int bid = blockIdx.x;
    int mode, local, gx, nwg, ldc;
    const bf16 *A, *B;
    if (bid < 48){        mode=0; local=bid;     gx=48; nwg=48;  A=bo_pad; B=WiT;   ldc=ISZ; }
    else if (bid < 336){  mode=1; local=bid-48;  gx=12; nwg=288; A=WiT;    B=Wobf;  ldc=HIDN; }
    else {                mode=2; local=bid-336; gx=36; nwg=576; A=hbf;    B=WqkvT; ldc=3*HIDN; }

    int cpx = nwg >> 3;
    int wg = (local & 7)*cpx + (local >> 3);   // nwg%8==0 for all segments
    int bn = wg % gx, bm = wg / gx;

    int t = threadIdx.x;
    int wave = t >> 6, lane = t & 63;
    int wm = (wave >> 1) << 5;
    int wn = (wave & 1) << 5;
    int lr = lane & 15, lg = lane >> 4;
    int x7 = lr & 7;
    int gb0 = ((lg    ) ^ x7) << 4;
    int gb1 = ((4 | lg) ^ x7) << 4;

    int srow = t >> 3;
    int glog = (t & 7) ^ (srow & 7);
    const bf16* Ag0 = A + (long)(bm*128 + srow)*HIDN + glog*8;
    const bf16* Ag1 = Ag0 + (long)64*HIDN;
    const bf16* Bg0 = B + (long)(bn*64 + srow)*HIDN + glog*8;

#define PSTAGE(buf,kt) { \
    gload16(Ag0 + (kt)*64, (bf16*)(hlds + (buf)*24576 + t*16)); \
    gload16(Ag1 + (kt)*64, (bf16*)(hlds + (buf)*24576 + 8192 + t*16)); \
    gload16(Bg0 + (kt)*64, (bf16*)(hlds + (buf)*24576 + 16384 + t*16)); }

    PSTAGE(0, 0);

    f32x4 acc[2][2] = {};

    #pragma unroll
    for (int kt = 0; kt < 12; ++kt){
        if (kt < 11) PSTAGE((kt+1)&1, kt+1);
        if (kt < 11) asm volatile("s_waitcnt vmcnt(3)" ::: "memory");
        else         asm volatile("s_waitcnt vmcnt(0)" ::: "memory");
        FENCE; __builtin_amdgcn_s_barrier(); FENCE;

        const char* Lb = hlds + (kt&1)*24576;
        short8 af[2][2], bfr[2][2];
        #pragma unroll
        for (int m=0;m<2;m++){
            const char* pr = Lb + (wm + m*16 + lr)*128;
            af[m][0] = *(const short8*)(pr + gb0);
            af[m][1] = *(const short8*)(pr + gb1);
        }
        #pragma unroll
        for (int n=0;n<2;n++){
            const char* pr = Lb + 16384 + (wn + n*16 + lr)*128;
            bfr[n][0] = *(const short8*)(pr + gb0);
            bfr[n][1] = *(const short8*)(pr + gb1);
        }
        __builtin_amdgcn_s_setprio(1);
        #pragma unroll
        for (int m=0;m<2;m++)
            #pragma unroll
            for (int n=0;n<2;n++)
                #pragma unroll
                for (int kk=0;kk<2;kk++)
                    acc[m][n] = __builtin_amdgcn_mfma_f32_16x16x32_bf16(af[m][kk], bfr[n][kk], acc[m][n], 0,0,0);
        __builtin_amdgcn_s_setprio(0);
        FENCE; __builtin_amdgcn_s_barrier(); FENCE;
    }
#undef PSTAGE

    #pragma unroll
    for (int m=0;m<2;m++){
        #pragma unroll
        for (int n=0;n<2;n++){
            int col = bn*64 + wn + n*16 + lr;
            #pragma unroll
            for (int i=0;i<4;i++){
                long row = (long)bm*128 + wm + m*16 + lg*4 + i;
                float v = acc[m][n][i];
                if (mode == 0){
                    if (row < NH) bhc[row*ISZ+col] = fmaf(w_kp[row], v, bi[col]);
                } else if (mode == 1){
                    WcT[row*HIDN+col] = f2bf(v * w_kp[col>>6]);
                } else {
                    qkv[row*(3*HIDN)+col] = f2bf(v + bqkv[col]);
                }
            }
        }
    }
}

// ---------------------------------------------------------------------------
// Fused flash attention v2 (max-free single pass + kt-split across 2 waves).
// 256 threads = 4 waves = 2 q-groups x 2 kt-halves. Max-free softmax makes
// split-K merging trivial: o = oA+oB, l = lA+lB (one __syncthreads).
// ---------------------------------------------------------------------------
__global__ __launch_bounds__(256)
void flash_attn(const bf16* __restrict__ qkv, const bf16* __restrict__ Vt,
                const float* __restrict__ mask, bf16* __restrict__ ctx2)
{
    __shared__ __align__(16) char p_lds[4*2048];    // per-wave P scratch
    __shared__ float mrg[2][64][21];                // kh=1 partials (pad 21: conflict-free)
    int z = blockIdx.y;
    int b = z / NH, h = z - b*NH;
    int t = threadIdx.x;
    int wave = t >> 6, lane = t & 63;
    int qg = wave >> 1, kh = wave & 1;
    int q0 = blockIdx.x*32 + qg*16;
    int lr = lane & 15, lg = lane >> 4;
    int x7 = lr & 7;
    int gb0 = ((lg    ) ^ x7) << 4;
    int gb1 = ((4 | lg) ^ x7) << 4;

    const bf16* Qp = qkv + (long)(b*SEQ + q0 + lr)*(3*HIDN) + h*HD + lg*8;
    short8 aq0 = *(const short8*)(Qp);
    short8 aq1 = *(const short8*)(Qp + 32);

    const bf16* Kb = qkv + (long)b*SEQ*(3*HIDN) + HIDN + h*HD + lg*8;
    const bf16* Vb = Vt + (long)z*HD*SEQ;
    const float* mb = mask + b*SEQ;
    char* pw = p_lds + wave*2048;

    f32x4 o[4] = {};
    float lsum[4] = {0.f,0.f,0.f,0.f};

    for (int kt = kh*4; kt < kh*4 + 4; ++kt){
        int kbase = kt*64;
        short8 bk0[4], bk1[4];
        #pragma unroll
        for (int nf=0;nf<4;nf++){
            const bf16* kp = Kb + (long)(kbase + nf*16 + lr)*(3*HIDN);
            bk0[nf] = *(const short8*)(kp);
            bk1[nf] = *(const short8*)(kp + 32);
        }
        f32x4 s[4] = {};
        #pragma unroll
        for (int nf=0;nf<4;nf++){
            s[nf] = __builtin_amdgcn_mfma_f32_16x16x32_bf16(aq0, bk0[nf], s[nf], 0,0,0);
            s[nf] = __builtin_amdgcn_mfma_f32_16x16x32_bf16(aq1, bk1[nf], s[nf], 0,0,0);
        }
        short8 bv0[4], bv1[4];
        #pragma unroll
        for (int nf=0;nf<4;nf++){
            const bf16* vp = Vb + (long)(nf*16 + lr)*SEQ + kbase + lg*8;
            bv0[nf] = *(const short8*)(vp);
            bv1[nf] = *(const short8*)(vp + 32);
        }
        #pragma unroll
        for (int nf=0;nf<4;nf++){
            float mk = mb[kbase + nf*16 + lr];
            int gk = nf*2 + (lr>>3);
            #pragma unroll
            for (int i=0;i<4;i++){
                int q = lg*4 + i;
                float e = __expf(fmaf(s[nf][i], 0.125f, mk));
                lsum[i] += e;
                *(bf16*)(pw + q*128 + ((gk ^ (q&7))<<4) + (lr&7)*2) = f2bf(e);
            }
        }
        short8 ap0 = *(const short8*)(pw + lr*128 + gb0);
        short8 ap1 = *(const short8*)(pw + lr*128 + gb1);
        #pragma unroll
        for (int nf=0;nf<4;nf++){
            o[nf] = __builtin_amdgcn_mfma_f32_16x16x32_bf16(ap0, bv0[nf], o[nf], 0,0,0);
            o[nf] = __builtin_amdgcn_mfma_f32_16x16x32_bf16(ap1, bv1[nf], o[nf], 0,0,0);
        }
    }

    // kt-split merge: kh=1 dumps partials; kh=0 combines after one barrier.
    if (kh == 1){
        float* m = &mrg[qg][lane][0];
        #pragma unroll
        for (int nf=0;nf<4;nf++)
            #pragma unroll
            for (int i=0;i<4;i++) m[nf*4+i] = o[nf][i];
        #pragma unroll
        for (int i=0;i<4;i++) m[16+i] = lsum[i];
    }
    __syncthreads();
    if (kh == 1) return;

    {
        const float* m = &mrg[qg][lane][0];
        #pragma unroll
        for (int nf=0;nf<4;nf++)
            #pragma unroll
            for (int i=0;i<4;i++) o[nf][i] += m[nf*4+i];
        #pragma unroll
        for (int i=0;i<4;i++) lsum[i] += m[16+i];
    }

    #pragma unroll
    for (int i=0;i<4;i++){
        float v = lsum[i];
        v += __shfl_xor(v, 1, 64);
        v += __shfl_xor(v, 2, 64);
        v += __shfl_xor(v, 4, 64);
        v += __shfl_xor(v, 8, 64);
        lsum[i] = __builtin_amdgcn_rcpf(v);
    }
    bf16* Cp = ctx2 + (long)(b*SEQ + q0)*HIDN + h*HD;
    #pragma unroll
    for (int nf=0;nf<4;nf++)
        #pragma unroll
        for (int i=0;i<4;i++)
            Cp[(long)(lg*4+i)*HIDN + nf*16 + lr] = f2bf(o[nf][i] * lsum[i]);
}

// ---------------------------------------------------------------------------
// Fused per-head FFN1 + head reduction — r10/r15 config, poly gelu.
// S[t][i] = sum_h w_a[h]*gelu( (ctx2[t]@WcT'[i])_h + bhc[h][i] )
// ---------------------------------------------------------------------------
__global__ __launch_bounds__(512)
void gemm_heads(const bf16* __restrict__ A, const bf16* __restrict__ B,
                bf16* __restrict__ S, const float* __restrict__ bhc,
                const float* __restrict__ w_a)
{
    __shared__ __align__(16) char hlds[2*24576 + 3072];
    char* bhcl = hlds + 49152;

    int nwg  = gridDim.x * gridDim.y;
    int orig = blockIdx.y * gridDim.x + blockIdx.x;
    int cpx = nwg >> 3;                       // nwg = 768, %8 == 0
    int wg = (orig & 7)*cpx + (orig >> 3);
    int bn = wg % gridDim.x, bm = wg / gridDim.x;

    int t = threadIdx.x;
    int wave = t >> 6, lane = t & 63;
    int wm = (wave >> 1) << 5;
    int wn = (wave & 1) << 5;
    int lr = lane & 15, lg = lane >> 4;
    int x7 = lr & 7;
    int gb0 = ((lg    ) ^ x7) << 4;
    int gb1 = ((4 | lg) ^ x7) << 4;

    int srow = t >> 3;
    int glog = (t & 7) ^ (srow & 7);
    const bf16* Ag0 = A + (long)(bm*128 + srow)*HIDN + glog*8;
    const bf16* Ag1 = Ag0 + (long)64*HIDN;
    const bf16* Bg0 = B + (long)(bn*64 + srow)*HIDN + glog*8;

    float wav[NH];
    #pragma unroll
    for (int h=0;h<NH;h++) wav[h] = w_a[h];

    if (t < 192){
        const float* src = bhc + (t>>4)*ISZ + bn*64 + (t&15)*4;
        gload16((const bf16*)src, (bf16*)(bhcl + t*16));
    }

#define HSTAGE(buf,h) { \
    gload16(Ag0 + (h)*64, (bf16*)(hlds + (buf)*24576 + t*16)); \
    gload16(Ag1 + (h)*64, (bf16*)(hlds + (buf)*24576 + 8192 + t*16)); \
    gload16(Bg0 + (h)*64, (bf16*)(hlds + (buf)*24576 + 16384 + t*16)); }

    HSTAGE(0, 0);

    f32x4 acc[2][2] = {};
    f32x4 sacc[2][2] = {};

    #pragma unroll
    for (int h = 0; h < NH; ++h){
        if (h < NH-1) HSTAGE((h+1)&1, h+1);
        if (h > 0){
            float bh0 = *(const float*)(bhcl + (h-1)*256 + (wn+lr)*4);
            float bh1 = *(const float*)(bhcl + (h-1)*256 + (wn+16+lr)*4);
            #pragma unroll
            for (int m=0;m<2;m++)
                #pragma unroll
                for (int n=0;n<2;n++)
                    #pragma unroll
                    for (int i=0;i<4;i++){
                        float v = acc[m][n][i] + (n ? bh1 : bh0);
                        sacc[m][n][i] = fmaf(wav[h-1], gelu_fast(v), sacc[m][n][i]);
                        acc[m][n][i] = 0.f;
                    }
        }
        if (h < NH-1) asm volatile("s_waitcnt vmcnt(3)" ::: "memory");
        else          asm volatile("s_waitcnt vmcnt(0)" ::: "memory");
        FENCE; __builtin_amdgcn_s_barrier(); FENCE;

        const char* Lb = hlds + (h&1)*24576;
        short8 af[2][2], bfr[2][2];
        #pragma unroll
        for (int m=0;m<2;m++){
            const char* pr = Lb + (wm + m*16 + lr)*128;
            af[m][0] = *(const short8*)(pr + gb0);
            af[m][1] = *(const short8*)(pr + gb1);
        }
        #pragma unroll
        for (int n=0;n<2;n++){
            const char* pr = Lb + 16384 + (wn + n*16 + lr)*128;
            bfr[n][0] = *(const short8*)(pr + gb0);
            bfr[n][1] = *(const short8*)(pr + gb1);
        }
        __builtin_amdgcn_s_setprio(1);
        #pragma unroll
        for (int m=0;m<2;m++)
            #pragma unroll
            for (int n=0;n<2;n++)
                #pragma unroll
                for (int kk=0;kk<2;kk++)
                    acc[m][n] = __builtin_amdgcn_mfma_f32_16x16x32_bf16(af[m][kk], bfr[n][kk], acc[m][n], 0,0,0);
        __builtin_amdgcn_s_setprio(0);
        FENCE; __builtin_amdgcn_s_barrier(); FENCE;
    }
#undef HSTAGE

    {   // final head merge
        float bh0 = *(const float*)(bhcl + (NH-1)*256 + (wn+lr)*4);
        float bh1 = *(const float*)(bhcl + (NH-1)*256 + (wn+16+lr)*4);
        #pragma unroll
        for (int m=0;m<2;m++)
            #pragma unroll
            for (int n=0;n<2;n++)
                #pragma unroll
                for (int i=0;i<4;i++){
                    float v = acc[m][n][i] + (n ? bh1 : bh0);
                    sacc[m][n][i] = fmaf(wav[NH-1], gelu_fast(v), sacc[m][n][i]);
                }
    }

    #pragma unroll
    for (int m=0;m<2;m++)
        #pragma unroll
        for (int n=0;n<2;n++)
            #pragma unroll
            for (int i=0;i<4;i++){
                long row = (long)bm*128 + wm + m*16 + lg*4 + i;
                S[row*ISZ + bn*64 + wn + n*16 + lr] = f2bf(sacc[m][n][i]);
            }
}

// ---------------------------------------------------------------------------
// One launch: weight transposes (blocks < 6336) + elementwise prep (rest).
// ---------------------------------------------------------------------------
#define NPREP (NTOK*HIDN + HIDN*HIDN + 128*HIDN + 3*HIDN)
__global__ __launch_bounds__(256)
void prep_all(const float* __restrict__ Wq, const float* __restrict__ Wk,
              const float* __restrict__ Wv, const float* __restrict__ Wi,
              const float* __restrict__ Wout,
              bf16* __restrict__ WqkvT, bf16* __restrict__ WiT,
              bf16* __restrict__ WoutT,
              const float* __restrict__ hidden, const float* __restrict__ Wo,
              const float* __restrict__ bq, const float* __restrict__ bk,
              const float* __restrict__ bv, const float* __restrict__ bo,
              bf16* __restrict__ hbf, bf16* __restrict__ Wobf,
              float* __restrict__ bqkv, bf16* __restrict__ bo_pad)
{
    __shared__ float tile[32][33];
    int bid = blockIdx.x;
    if (bid >= 6336){
        int i = (bid-6336)*256 + threadIdx.x;
        const int n1 = NTOK*HIDN, n2 = HIDN*HIDN, n3 = 128*HIDN;
        if (i < n1) hbf[i] = f2bf(hidden[i]);
        int j = i - n1;
        if (j >= 0 && j < n2) Wobf[j] = f2bf(Wo[j]);
        int k = i - n1 - n2;
        if (k >= 0 && k < n3) bo_pad[k] = (k < NH*HIDN) ? f2bf(bo[k]) : f2bf(0.f);
        int l = i - n1 - n2 - n3;
        if (l >= 0 && l < 3*HIDN)
            bqkv[l] = (l < HIDN) ? bq[l] : (l < 2*HIDN ? bk[l-HIDN] : bv[l-2*HIDN]);
        return;
    }
    const float* src; bf16* dst; int R, C, ct, rem;
    if (bid < 1728){
        int z = bid / 576; rem = bid - z*576;
        src = (z==0) ? Wq : ((z==1) ? Wk : Wv);
        dst = WqkvT + (long)z*HIDN*HIDN;
        R = HIDN; C = HIDN; ct = 24;
    } else if (bid < 4032){
        rem = bid - 1728; src = Wi; dst = WiT; R = HIDN; C = ISZ; ct = 96;
    } else {
        rem = bid - 4032; src = Wout; dst = WoutT; R = ISZ; C = HIDN; ct = 24;
    }
    int c0 = (rem % ct)*32, r0 = (rem / ct)*32;
    int tx = threadIdx.x & 31, ty = threadIdx.x >> 5;
    #pragma unroll
    for (int i=0;i<32;i+=8) tile[ty+i][tx] = src[(long)(r0+ty+i)*C + c0+tx];
    __syncthreads();
    #pragma unroll
    for (int i=0;i<32;i+=8) dst[(long)(c0+ty+i)*R + r0+tx] = f2bf(tile[tx][ty+i]);
}

// bf16 V transpose: per z=(b,h): qkv V-slice [512 s][64 d] -> Vt[z][64 d][512 s]
__global__ __launch_bounds__(256)
void transpose_v(const bf16* __restrict__ qkv, bf16* __restrict__ Vt)
{
    __shared__ bf16 tile[32][33];
    int za = blockIdx.z; int b = za/NH, h = za - b*NH;
    const bf16* src = qkv + (long)b*SEQ*3*HIDN + 2*HIDN + h*HD;
    bf16* dst = Vt + (long)za*HD*SEQ;
    int d0 = blockIdx.x*32, s0 = blockIdx.y*32;
    int tx = threadIdx.x & 31, ty = threadIdx.x >> 5;
    #pragma unroll
    for (int i=0;i<32;i+=8) tile[ty+i][tx] = src[(long)(s0+ty+i)*(3*HIDN) + d0+tx];
    __syncthreads();
    #pragma unroll
    for (int i=0;i<32;i+=8) dst[(long)(d0+ty+i)*SEQ + s0+tx] = tile[tx][ty+i];
}

// out = LN(hidden + sum_z part_bf16[z] + swa*bout), float4/ushort4 loads.
__global__ __launch_bounds__(192)
void add_ln(const float4* __restrict__ hidden, const u16x4* __restrict__ part,
            const float4* __restrict__ bout, const float* __restrict__ w_a,
            const float4* __restrict__ gamma, const float4* __restrict__ beta,
            float4* __restrict__ out)
{
    __shared__ float red[6];
    int row = blockIdx.x;
    int t = threadIdx.x;          // 0..191
    int wave = t >> 6, lane = t & 63;
    float swa = 0.f;
    #pragma unroll
    for (int h=0;h<NH;h++) swa += w_a[h];

    long idx = (long)row*192 + t;
    float4 x = hidden[idx];
    #pragma unroll
    for (int z=0;z<4;z++){
        u16x4 p = part[(long)z*NTOK*192 + idx];
        x.x += bf2f(p.x); x.y += bf2f(p.y); x.z += bf2f(p.z); x.w += bf2f(p.w);
    }
    float4 bo4 = bout[t];
    x.x += swa*bo4.x; x.y += swa*bo4.y; x.z += swa*bo4.z; x.w += swa*bo4.w;

    float sum = x.x + x.y + x.z + x.w;
    #pragma unroll
    for (int o=32;o>0;o>>=1) sum += __shfl_xor(sum,o,64);
    if (lane==0) red[wave] = sum;
    __syncthreads();
    sum = red[0] + red[1] + red[2];
    float u = sum * (1.0f/768.0f);

    float dx = x.x-u, dy = x.y-u, dz = x.z-u, dw = x.w-u;
    float vs = dx*dx + dy*dy + dz*dz + dw*dw;
    #pragma unroll
    for (int o=32;o>0;o>>=1) vs += __shfl_xor(vs,o,64);
    if (lane==0) red[3+wave] = vs;
    __syncthreads();
    vs = red[3] + red[4] + red[5];
    float rstd = rsqrtf(vs*(1.0f/768.0f) + 1e-12f);

    float4 g = gamma[t], b = beta[t];
    float4 r;
    r.x = g.x*dx*rstd + b.x;
    r.y = g.y*dy*rstd + b.y;
    r.z = g.z*dz*rstd + b.z;
    r.w = g.w*dw*rstd + b.w;
    out[idx] = r;
}

extern "C" void kernel_launch(void* const* d_in, const int* in_sizes, int n_in,
                              void* d_out, int out_size, void* d_ws, size_t ws_size,
                              hipStream_t stream)
{
    const float* hidden = (const float*)d_in[0];
    const float* mask   = (const float*)d_in[1];
    const float* Wq = (const float*)d_in[2];
    const float* bq = (const float*)d_in[3];
    const float* Wk = (const float*)d_in[4];
    const float* bk = (const float*)d_in[5];
    const float* Wv = (const float*)d_in[6];
    const float* bv = (const float*)d_in[7];
    const float* Wo = (const float*)d_in[8];
    const float* bo = (const float*)d_in[9];
    const float* w_kp = (const float*)d_in[10];
    const float* w_a  = (const float*)d_in[11];
    const float* Wi = (const float*)d_in[12];
    const float* bi = (const float*)d_in[13];
    const float* Wout = (const float*)d_in[14];
    const float* boutp = (const float*)d_in[15];
    const float* gamma = (const float*)d_in[16];
    const float* beta  = (const float*)d_in[17];
    float* out = (float*)d_out;

    char* w = (char*)d_ws;
    auto alloc = [&](size_t bytes)->char* {
        char* p = w; w += (bytes + 255) & ~(size_t)255; return p;
    };
    bf16*  hbf    = (bf16*) alloc((size_t)NTOK*HIDN*2);
    bf16*  WqkvT  = (bf16*) alloc((size_t)3*HIDN*HIDN*2);
    float* bqkv   = (float*)alloc((size_t)3*HIDN*4);
    bf16*  WiT    = (bf16*) alloc((size_t)ISZ*HIDN*2);
    bf16*  WoutT  = (bf16*) alloc((size_t)HIDN*ISZ*2);
    bf16*  Wobf   = (bf16*) alloc((size_t)HIDN*HIDN*2);
    bf16*  WcT    = (bf16*) alloc((size_t)ISZ*HIDN*2);
    bf16*  bo_pad = (bf16*) alloc((size_t)128*HIDN*2);
    float* bhc    = (float*)alloc((size_t)NH*ISZ*4);
    bf16*  part   = (bf16*) alloc((size_t)4*NTOK*HIDN*2);   // split-K partials (bf16)
    bf16*  qkv    = (bf16*) alloc((size_t)NTOK*3*HIDN*2);
    bf16*  ctx2   = (bf16*) alloc((size_t)NTOK*HIDN*2);
    bf16*  Sbuf   = (bf16*) alloc((size_t)NTOK*ISZ*2);
    bf16*  Vt     = (bf16*) alloc((size_t)NH*4*HD*SEQ*2);

    // ---- prep (transposes + elementwise, one launch) ----
    prep_all<<<6336 + (NPREP+255)/256, 256, 0, stream>>>(
        Wq, Wk, Wv, Wi, Wout, WqkvT, WiT, WoutT,
        hidden, Wo, bq, bk, bv, bo, hbf, Wobf, bqkv, bo_pad);

    // ---- fused pre-GEMMs: bhc + WcT + QKV in one launch ----
    gemm_pre<<<912, 512, 0, stream>>>(
        WiT, Wobf, bo_pad, hbf, WqkvT,
        WcT, bhc, qkv, w_kp, bi, bqkv);

    // ---- attention ----
    transpose_v<<<dim3(2,16,48), 256, 0, stream>>>(qkv, Vt);
    flash_attn<<<dim3(SEQ/32, 48), 256, 0, stream>>>(qkv, Vt, mask, ctx2);

    // ---- fused per-head FFN1 + head-reduce -> S ----
    gemm_heads<<<dim3(ISZ/64, NTOK/128), 512, 0, stream>>>(
        ctx2, WcT, Sbuf, bhc, w_a);

    // ---- FFN2': part[z] = S[:, z*768:(z+1)*768] @ WoutT[:, z*768:(z+1)*768]^T (bf16) ----
    gemm_pipe<1><<<dim3(HIDN/64, NTOK/128, 4), 512, 0, stream>>>(
        Sbuf, WoutT, part, nullptr,
        ISZ, ISZ, HIDN,
        768, 768, (long)NTOK*HIDN);

    // ---- residual + partial-sum + swa*bout + LayerNorm ----
    add_ln<<<NTOK, 192, 0, stream>>>(
        (const float4*)hidden, (const u16x4*)part, (const float4*)boutp,
        w_a, (const float4*)gamma, (const float4*)beta, (float4*)out);
}